// Round 3
// baseline (268.333 us; speedup 1.0000x reference)
//
#include <hip/hip_runtime.h>
#include <stdint.h>

// B=4, S=2048, d=1024. fp32 in/out, f16 MFMA internally.
// cvt(x,W) -> QKV gemm (256^2 8-phase engine) -> transpose V ->
// scores gemm (same engine, causal block-skip, batched z) ->
// column stats (softmax over axis=1!) -> PV gemm (fused P=exp(s-m_j)/Z_j).

typedef __attribute__((ext_vector_type(8))) _Float16 half8;
typedef __attribute__((ext_vector_type(4))) float f32x4;
typedef __attribute__((ext_vector_type(8))) unsigned short ushort8;

__device__ __forceinline__ ushort f2h(float f) {
  _Float16 h = (_Float16)f;
  union { _Float16 h; ushort u; } v; v.h = h; return v.u;
}

__device__ __forceinline__ void gload_lds16(const ushort* g, ushort* l) {
  __builtin_amdgcn_global_load_lds(
      (const __attribute__((address_space(1))) void*)g,
      (__attribute__((address_space(3))) void*)l, 16, 0, 0);
}

// ---------------- convert / transpose kernels ----------------
__global__ void k_cvt_x(const float* __restrict__ x, ushort* __restrict__ xh) {
  int i = (blockIdx.x * 256 + threadIdx.x) * 4;
  float4 v = *(const float4*)(x + i);
  ushort4 o;
  o.x = f2h(v.x); o.y = f2h(v.y); o.z = f2h(v.z); o.w = f2h(v.w);
  *(ushort4*)(xh + i) = o;
}

__global__ void k_cvt_w(const float* __restrict__ Wq, const float* __restrict__ Wk,
                        const float* __restrict__ Wv, ushort* __restrict__ Wt) {
  __shared__ ushort tile[32][33];
  const float* W = blockIdx.z == 0 ? Wq : blockIdx.z == 1 ? Wk : Wv;
  int e0 = blockIdx.x * 32, d0 = blockIdx.y * 32;
  for (int r = threadIdx.y; r < 32; r += 8)
    tile[r][threadIdx.x] = f2h(W[(size_t)(d0 + r) * 1024 + e0 + threadIdx.x]);
  __syncthreads();
  ushort* out = Wt + (size_t)blockIdx.z * 1024 * 1024;
  for (int r = threadIdx.y; r < 32; r += 8)
    out[(size_t)(e0 + r) * 1024 + d0 + threadIdx.x] = tile[threadIdx.x][r];
}

// V f16 [b*2048+j][e] -> Vt [b][e][j]
__global__ void k_tr_v(const ushort* __restrict__ V, ushort* __restrict__ Vt) {
  __shared__ ushort tile[32][33];
  int b = blockIdx.z;
  int e0 = blockIdx.x * 32, j0 = blockIdx.y * 32;
  const ushort* src = V + (size_t)b * 2048 * 1024;
  for (int r = threadIdx.y; r < 32; r += 8)
    tile[r][threadIdx.x] = src[(size_t)(j0 + r) * 1024 + e0 + threadIdx.x];
  __syncthreads();
  ushort* dst = Vt + (size_t)b * 1024 * 2048;
  for (int r = threadIdx.y; r < 32; r += 8)
    dst[(size_t)(e0 + r) * 2048 + j0 + threadIdx.x] = tile[threadIdx.x][r];
}

// ============== 256x256 8-phase GEMM engine (T1+T2+T3+T4+T5) ==============
// 512 threads = 8 waves (2M x 4N), per-wave output 128x64, BK=64, K=1024.
// LDS: 2 x (256x64) A + 2 x (256x64) B f16 = 128 KiB, double buffered.
// Tile k+1 staged (8 global_load_lds/wave) at group-k entry; counted vmcnt(8).
// XOR swizzle: phys_half = row*64 + (col ^ ((row&7)<<3)); inverse-swizzled
// global source (gload writes LDS linearly), swizzled ds_read.
// EPI 0: QKV split (f16 x3, XCD-swizzled 1-D grid 384)
// EPI 1: scores (f32, *1/32, causal mask, skip bn>bm, z = batch)
template <int EPI>
__global__ __launch_bounds__(512, 2)
void k_gemm256(const ushort* __restrict__ A, const ushort* __restrict__ Bt,
               void* o0, void* o1, void* o2) {
  constexpr int NK = 16;  // K = 1024
  int bm, bn;
  if (EPI == 0) {
    int wg = blockIdx.x;                    // 384 = 32x12, 384%8==0 -> bijective
    int swz = (wg & 7) * 48 + (wg >> 3);
    bm = swz / 12; bn = swz % 12;
  } else {
    bm = blockIdx.y; bn = blockIdx.x;
    if (bn > bm) return;                    // fully-masked causal tile
    size_t boff = (size_t)blockIdx.z * (2048 * 1024);
    A += boff; Bt += boff;
  }

  __shared__ __align__(16) ushort As[2][256 * 64];
  __shared__ __align__(16) ushort Bs[2][256 * 64];

  const int t = threadIdx.x;
  const int lane = t & 63;
  const int wv = t >> 6;
  const int wm = (wv >> 2) * 128;
  const int wn = (wv & 3) * 64;
  const int l15 = lane & 15;

  // staging: thread t covers row c*64 + t/8, logical col chunk swizzled so
  // that the linear gload dest receives the right element (rule 21)
  const int r64 = t >> 3;
  const int colswz = ((t & 7) * 8) ^ (((t >> 3) & 7) * 8);
  const ushort* gA = A + (size_t)(bm * 256) * 1024 + colswz;
  const ushort* gB = Bt + (size_t)(bn * 256) * 1024 + colswz;

  // fragment read offsets (halves): row*64 + (col ^ ((row&7)<<3)), row&7==lane&7
  int rowA[8], rowB[4];
#pragma unroll
  for (int i = 0; i < 8; ++i) rowA[i] = (wm + i * 16 + l15) * 64;
#pragma unroll
  for (int j = 0; j < 4; ++j) rowB[j] = (wn + j * 16 + l15) * 64;
  const int colk0 = (((lane >> 4) * 8)) ^ ((lane & 7) * 8);
  const int colk1 = (32 + ((lane >> 4) * 8)) ^ ((lane & 7) * 8);

  f32x4 acc[8][4] = {};
  half8 af[4][2], bf[2][2];

#define STAGE(kt)                                                              \
  {                                                                            \
    const ushort* sa = gA + (kt) * 64;                                         \
    const ushort* sb = gB + (kt) * 64;                                         \
    ushort* la = &As[(kt) & 1][t * 8];                                         \
    ushort* lb = &Bs[(kt) & 1][t * 8];                                         \
    _Pragma("unroll") for (int c = 0; c < 4; ++c)                              \
        gload_lds16(sa + (size_t)(c * 64 + r64) * 1024, la + c * 4096);        \
    _Pragma("unroll") for (int c = 0; c < 4; ++c)                              \
        gload_lds16(sb + (size_t)(c * 64 + r64) * 1024, lb + c * 4096);        \
  }
#define LDA4(iset)                                                             \
  { _Pragma("unroll") for (int ii = 0; ii < 4; ++ii) {                         \
      int rr = rowA[(iset) * 4 + ii];                                          \
      af[ii][0] = *(const half8*)&Ab[rr + colk0];                              \
      af[ii][1] = *(const half8*)&Ab[rr + colk1]; } }
#define LDB2(jset)                                                             \
  { _Pragma("unroll") for (int jj = 0; jj < 2; ++jj) {                         \
      int rr = rowB[(jset) * 2 + jj];                                          \
      bf[jj][0] = *(const half8*)&Bb[rr + colk0];                              \
      bf[jj][1] = *(const half8*)&Bb[rr + colk1]; } }
#define MM(iset, jset)                                                         \
  {                                                                            \
    __builtin_amdgcn_s_setprio(1);                                             \
    _Pragma("unroll") for (int ii = 0; ii < 4; ++ii)                           \
        _Pragma("unroll") for (int jj = 0; jj < 2; ++jj) {                     \
      acc[(iset) * 4 + ii][(jset) * 2 + jj] =                                  \
          __builtin_amdgcn_mfma_f32_16x16x32_f16(                              \
              af[ii][0], bf[jj][0], acc[(iset) * 4 + ii][(jset) * 2 + jj], 0, 0, 0); \
      acc[(iset) * 4 + ii][(jset) * 2 + jj] =                                  \
          __builtin_amdgcn_mfma_f32_16x16x32_f16(                              \
              af[ii][1], bf[jj][1], acc[(iset) * 4 + ii][(jset) * 2 + jj], 0, 0, 0); \
    }                                                                          \
    __builtin_amdgcn_s_setprio(0);                                             \
  }
#define PHB                                                                    \
  { __builtin_amdgcn_s_barrier(); __builtin_amdgcn_sched_barrier(0); }

  STAGE(0);
  for (int kt = 0; kt < NK; ++kt) {
    // group entry: issue next tile (its buffer was fully read one group ago),
    // then counted wait for THIS tile's 8 loads, then sync all waves.
    if (kt + 1 < NK) {
      STAGE(kt + 1);
      asm volatile("s_waitcnt vmcnt(8)" ::: "memory");
    } else {
      asm volatile("s_waitcnt vmcnt(0)" ::: "memory");
    }
    PHB;
    const ushort* Ab = As[kt & 1];
    const ushort* Bb = Bs[kt & 1];
    // 4 quadrant phases, snake order (A then B reuse)
    LDA4(0); LDB2(0); PHB; MM(0, 0); PHB;
    LDB2(1);          PHB; MM(0, 1); PHB;
    LDA4(1);          PHB; MM(1, 1); PHB;
    LDB2(0);          PHB; MM(1, 0); PHB;
  }
#undef STAGE
#undef LDA4
#undef LDB2
#undef MM
#undef PHB

  int rowbase = bm * 256 + wm + ((lane >> 4) << 2);
  if (EPI == 0) {
    int mat = bn >> 2;  // 256-col tiles never straddle the 1024 boundaries
    ushort* dst = mat == 0 ? (ushort*)o0 : mat == 1 ? (ushort*)o1 : (ushort*)o2;
    int colbase = (bn & 3) * 256 + wn + l15;
#pragma unroll
    for (int i = 0; i < 8; ++i)
#pragma unroll
      for (int j = 0; j < 4; ++j)
#pragma unroll
        for (int r = 0; r < 4; ++r)
          dst[(size_t)(rowbase + i * 16 + r) * 1024 + colbase + j * 16] =
              f2h(acc[i][j][r]);
  } else {
    float* sc = (float*)o0 + (size_t)blockIdx.z * 4194304;
    int colbase = bn * 256 + wn + l15;
#pragma unroll
    for (int i = 0; i < 8; ++i)
#pragma unroll
      for (int j = 0; j < 4; ++j)
#pragma unroll
        for (int r = 0; r < 4; ++r) {
          int row = rowbase + i * 16 + r;
          int col = colbase + j * 16;
          float vv = acc[i][j][r] * 0.03125f;  // 1/sqrt(1024)
          if (col > row) vv = -1e30f;          // causal (j > i)
          sc[(size_t)row * 2048 + col] = vv;
        }
  }
}

// ---------------- column softmax stats (softmax over i, per column j) --------
__global__ void k_stats1(const float* __restrict__ Sc, float* __restrict__ pm,
                         float* __restrict__ pz) {
  int b = blockIdx.z;
  const float* S = Sc + (size_t)b * 4194304;
  int j0 = (blockIdx.x * 256 + threadIdx.x) * 4;
  int i0 = blockIdx.y * 128;
  size_t po = ((size_t)b * 16 + blockIdx.y) * 2048 + j0;
  if (i0 + 127 < j0) {  // whole chunk masked: never touch (poison) memory
    f32x4 mneg = {-1e30f, -1e30f, -1e30f, -1e30f};
    f32x4 zz = {0.f, 0.f, 0.f, 0.f};
    *(f32x4*)&pm[po] = mneg;
    *(f32x4*)&pz[po] = zz;
    return;
  }
  f32x4 m = {-1e30f, -1e30f, -1e30f, -1e30f};
  f32x4 z = {0.f, 0.f, 0.f, 0.f};
  for (int i = i0; i < i0 + 128; ++i) {
    f32x4 s = *(const f32x4*)&S[(size_t)i * 2048 + j0];
    int d = i - j0;
#pragma unroll
    for (int c = 0; c < 4; ++c) {
      float sv = (d >= c) ? s[c] : -1e30f;
      float nm = fmaxf(m[c], sv);
      z[c] = z[c] * __expf(m[c] - nm) + __expf(sv - nm);
      m[c] = nm;
    }
  }
  *(f32x4*)&pm[po] = m;
  *(f32x4*)&pz[po] = z;
}

__global__ void k_stats2(const float* __restrict__ pm, const float* __restrict__ pz,
                         float* __restrict__ cm, float* __restrict__ cz) {
  int b = blockIdx.z;
  int j = blockIdx.x * 256 + threadIdx.x;
  float m = -1e30f;
#pragma unroll
  for (int c = 0; c < 16; ++c) m = fmaxf(m, pm[((size_t)b * 16 + c) * 2048 + j]);
  float zs = 0.f;
#pragma unroll
  for (int c = 0; c < 16; ++c)
    zs += pz[((size_t)b * 16 + c) * 2048 + j] * __expf(pm[((size_t)b * 16 + c) * 2048 + j] - m);
  cm[(size_t)b * 2048 + j] = m;
  cz[(size_t)b * 2048 + j] = zs > 0.f ? 1.0f / zs : 0.f;
}

// -------- PV gemm: A = P (fused exp from Sc), B = Vt; causal K-truncation ----
__global__ __launch_bounds__(256)
void k_pv(const float* __restrict__ Sc, const float* __restrict__ cm,
          const float* __restrict__ cz, const ushort* __restrict__ Vt,
          float* __restrict__ out) {
  int b = blockIdx.z;
  int bm = blockIdx.y, bn = blockIdx.x;
  const float* S = Sc + (size_t)b * 4194304;
  const float* cmb = cm + (size_t)b * 2048;
  const float* czb = cz + (size_t)b * 2048;
  const ushort* Vb = Vt + (size_t)b * 2097152;
  float* ob = out + (size_t)b * 2097152;

  __shared__ __align__(16) ushort As[128 * 64];
  __shared__ __align__(16) ushort Bs[128 * 64];
  int t = threadIdx.x;
  int lane = t & 63, wave = t >> 6;
  int wm = (wave >> 1) * 64, wn = (wave & 1) * 64;
  f32x4 acc[4][4] = {};

  int r0 = t >> 3, c0 = (t & 7) * 8;
  const int nk = 2 * bm + 2;  // P cols nonzero only for j <= 128*bm+127
  for (int kt = 0; kt < nk; ++kt) {
    const ushort* gb = Vb + (size_t)(bn * 128) * 2048 + kt * 64;
#pragma unroll
    for (int it = 0; it < 4; ++it) {
      int r = it * 32 + r0;
      gload_lds16(gb + (size_t)r * 2048 + c0, &Bs[(it * 256 + t) * 8]);
    }
    int j0 = kt * 64 + c0;
    f32x4 m0 = *(const f32x4*)&cmb[j0];
    f32x4 m1 = *(const f32x4*)&cmb[j0 + 4];
    f32x4 z0 = *(const f32x4*)&czb[j0];
    f32x4 z1 = *(const f32x4*)&czb[j0 + 4];
#pragma unroll
    for (int it = 0; it < 4; ++it) {
      int r = it * 32 + r0;
      const float* src = &S[(size_t)(bm * 128 + r) * 2048 + j0];
      f32x4 a = *(const f32x4*)src;
      f32x4 c = *(const f32x4*)(src + 4);
      ushort8 p;
#pragma unroll
      for (int q = 0; q < 4; ++q) p[q] = f2h(__expf(a[q] - m0[q]) * z0[q]);
#pragma unroll
      for (int q = 0; q < 4; ++q) p[4 + q] = f2h(__expf(c[q] - m1[q]) * z1[q]);
      *(ushort8*)&As[r * 64 + c0] = p;
    }
    __syncthreads();
#pragma unroll
    for (int kk = 0; kk < 2; ++kk) {
      half8 af[4], bfr[4];
#pragma unroll
      for (int i = 0; i < 4; ++i) {
        af[i] = *(const half8*)&As[(wm + i * 16 + (lane & 15)) * 64 + kk * 32 + (lane >> 4) * 8];
        bfr[i] = *(const half8*)&Bs[(wn + i * 16 + (lane & 15)) * 64 + kk * 32 + (lane >> 4) * 8];
      }
#pragma unroll
      for (int i = 0; i < 4; ++i)
#pragma unroll
        for (int j = 0; j < 4; ++j)
          acc[i][j] = __builtin_amdgcn_mfma_f32_16x16x32_f16(af[i], bfr[j], acc[i][j], 0, 0, 0);
    }
    __syncthreads();
  }

  int row0 = bm * 128 + wm + ((lane >> 4) << 2);
  int col0 = bn * 128 + wn + (lane & 15);
#pragma unroll
  for (int i = 0; i < 4; ++i)
#pragma unroll
    for (int j = 0; j < 4; ++j) {
      int col = col0 + j * 16;
#pragma unroll
      for (int r = 0; r < 4; ++r)
        ob[(size_t)(row0 + i * 16 + r) * 1024 + col] = acc[i][j][r];
    }
}

// ---------------- host ----------------
extern "C" void kernel_launch(void* const* d_in, const int* in_sizes, int n_in,
                              void* d_out, int out_size, void* d_ws, size_t ws_size,
                              hipStream_t stream) {
  const float* x  = (const float*)d_in[0];
  const float* Wq = (const float*)d_in[1];
  const float* Wk = (const float*)d_in[2];
  const float* Wv = (const float*)d_in[3];
  float* out = (float*)d_out;
  char* ws = (char*)d_ws;

  ushort* Qh = (ushort*)(ws);                 // 16,777,216
  ushort* Kh = (ushort*)(ws + 16777216);      // 16,777,216
  ushort* Vt = (ushort*)(ws + 33554432);      // 16,777,216
  float*  Sc = (float*) (ws + 50331648);      // 4 x 2048*2048*4 = 67,108,864
  // transient (dead before Sc is written):
  ushort* xh = (ushort*)(ws + 50331648);      // dead after QKV
  ushort* Wt = (ushort*)(ws + 67108864);      // dead after QKV
  ushort* Vh = (ushort*)(ws + 73400320);      // dead after tr_v
  // stats live after Qh region... (distinct offsets, Qh still live) -> put at tail
  float*  pm = (float*) (ws + 117440512);     // 524,288
  float*  pz = (float*) (ws + 117964800);     // 524,288
  float*  cm = (float*) (ws + 118489088);     // 32,768
  float*  cz = (float*) (ws + 118521856);     // 32,768  (end ~118.6 MB)

  k_cvt_x<<<8192, 256, 0, stream>>>(x, xh);
  k_cvt_w<<<dim3(32, 32, 3), dim3(32, 8), 0, stream>>>(Wq, Wk, Wv, Wt);
  // fused QKV projection: A = xh [8192x1024], Bt = Wt [3072x1024]
  k_gemm256<0><<<384, 512, 0, stream>>>(xh, Wt, Qh, Kh, Vh);
  k_tr_v<<<dim3(32, 64, 4), dim3(32, 8), 0, stream>>>(Vh, Vt);
  // scores, batched over z: C[i][j] = Q_i . K_j
  k_gemm256<1><<<dim3(8, 8, 4), 512, 0, stream>>>(Qh, Kh, Sc, nullptr, nullptr);
  k_stats1<<<dim3(2, 16, 4), 256, 0, stream>>>(Sc, pm, pz);
  k_stats2<<<dim3(8, 1, 4), 256, 0, stream>>>(pm, pz, cm, cz);
  // context: A = P(fused) [2048x2048], B = Vt (K truncated per row-block)
  k_pv<<<dim3(8, 16, 4), 256, 0, stream>>>(Sc, cm, cz, Vt, out);
}

// Round 4
// 236.953 us; speedup vs baseline: 1.1324x; 1.1324x over previous
//
#include <hip/hip_runtime.h>
#include <stdint.h>

// B=4, S=2048, d=1024. fp32 in/out, f16 MFMA internally.
// cvt(x,W) -> QKV gemm (128^2, BK=32, TRIPLE-buffered, counted vmcnt(4)) ->
// transpose V -> scores gemm (same engine, causal skip, fused column-stats) ->
// stats2 -> PV gemm (BN=256, fused P=exp(s-m_j)/Z_j, swizzled LDS).

typedef __attribute__((ext_vector_type(8))) _Float16 half8;
typedef __attribute__((ext_vector_type(4))) float f32x4;
typedef __attribute__((ext_vector_type(8))) unsigned short ushort8;

__device__ __forceinline__ ushort f2h(float f) {
  _Float16 h = (_Float16)f;
  union { _Float16 h; ushort u; } v; v.h = h; return v.u;
}

__device__ __forceinline__ void gload_lds16(const ushort* g, ushort* l) {
  __builtin_amdgcn_global_load_lds(
      (const __attribute__((address_space(1))) void*)g,
      (__attribute__((address_space(3))) void*)l, 16, 0, 0);
}

// ---------------- convert / transpose kernels ----------------
__global__ void k_cvt_x(const float* __restrict__ x, ushort* __restrict__ xh) {
  int i = (blockIdx.x * 256 + threadIdx.x) * 4;
  float4 v = *(const float4*)(x + i);
  ushort4 o;
  o.x = f2h(v.x); o.y = f2h(v.y); o.z = f2h(v.z); o.w = f2h(v.w);
  *(ushort4*)(xh + i) = o;
}

__global__ void k_cvt_w(const float* __restrict__ Wq, const float* __restrict__ Wk,
                        const float* __restrict__ Wv, ushort* __restrict__ Wt) {
  __shared__ ushort tile[32][33];
  const float* W = blockIdx.z == 0 ? Wq : blockIdx.z == 1 ? Wk : Wv;
  int e0 = blockIdx.x * 32, d0 = blockIdx.y * 32;
  for (int r = threadIdx.y; r < 32; r += 8)
    tile[r][threadIdx.x] = f2h(W[(size_t)(d0 + r) * 1024 + e0 + threadIdx.x]);
  __syncthreads();
  ushort* out = Wt + (size_t)blockIdx.z * 1024 * 1024;
  for (int r = threadIdx.y; r < 32; r += 8)
    out[(size_t)(e0 + r) * 1024 + d0 + threadIdx.x] = tile[threadIdx.x][r];
}

// V f16 [b*2048+j][e] -> Vt [b][e][j]
__global__ void k_tr_v(const ushort* __restrict__ V, ushort* __restrict__ Vt) {
  __shared__ ushort tile[32][33];
  int b = blockIdx.z;
  int e0 = blockIdx.x * 32, j0 = blockIdx.y * 32;
  const ushort* src = V + (size_t)b * 2048 * 1024;
  for (int r = threadIdx.y; r < 32; r += 8)
    tile[r][threadIdx.x] = src[(size_t)(j0 + r) * 1024 + e0 + threadIdx.x];
  __syncthreads();
  ushort* dst = Vt + (size_t)b * 1024 * 2048;
  for (int r = threadIdx.y; r < 32; r += 8)
    dst[(size_t)(e0 + r) * 2048 + j0 + threadIdx.x] = tile[threadIdx.x][r];
}

// ======= 128x128 GEMM engine: BK=32, triple-buffer, counted vmcnt(4) =======
// 256 thr = 4 waves (2Mx2N), per-wave 64x64 out, K=1024 -> 32 K-tiles.
// LDS per buf: A/B 128x32 f16 = 8 KB each; 3 bufs = 48 KB -> 3 blocks/CU.
// 2-bit XOR swizzle on 16B chunks: phys_chunk = chunk ^ (row&3); staged via
// inverse-swizzled global source (gload dest linear), read swizzled.
// Per tile: STAGE(kt+2) [4 gloads] after counted vmcnt(4)+barrier; 8 ds_read;
// setprio around 16 MFMA. One barrier + one sched_barrier per tile.
// EPI 0: QKV split (f16 x3), 1-D grid 1536, XCD-chunked. EPI 1: scores
// (f32, scale+causal, skip bn>bm, z=batch) + FUSED column (m,z) partials.
template <int EPI>
__global__ __launch_bounds__(256)
void k_gemm32(const ushort* __restrict__ A, const ushort* __restrict__ Bt,
              void* o0, void* o1, void* o2,
              float* __restrict__ pm, float* __restrict__ pz) {
  int bm, bn, bz = 0;
  if (EPI == 0) {
    int wg = blockIdx.x;                        // 1536 = 8 * 192, bijective
    int swz = (wg & 7) * 192 + (wg >> 3);
    bm = swz / 24; bn = swz % 24;
  } else {
    bm = blockIdx.y; bn = blockIdx.x; bz = blockIdx.z;
    if (bn > bm) return;                        // fully-masked causal tile
    A  += (size_t)bz * 2097152;
    Bt += (size_t)bz * 2097152;
  }
  __shared__ __align__(16) ushort As[3][128 * 32];
  __shared__ __align__(16) ushort Bs[3][128 * 32];
  __shared__ float red[4][4][16][2];

  const int t = threadIdx.x, lane = t & 63, wv = t >> 6;
  const int wm = (wv >> 1) * 64, wn = (wv & 1) * 64, l15 = lane & 15;
  // staging: thread t -> rows (t>>2)+64c, dest chunk t&3; source col chunk
  // inverse-swizzled so linear dest holds logical (row, chunk^(row&3)).
  const int srcc = (((t & 3) ^ ((t >> 2) & 3)) * 8);
  const ushort* ga = A + (size_t)(bm * 128 + (t >> 2)) * 1024 + srcc;
  const ushort* gb = Bt + (size_t)(bn * 128 + (t >> 2)) * 1024 + srcc;
  const int dst0 = t * 8;

  int rA[4], rB[4];
#pragma unroll
  for (int i = 0; i < 4; ++i) {
    rA[i] = (wm + i * 16 + l15) * 32;
    rB[i] = (wn + i * 16 + l15) * 32;
  }
  const int ck = (((lane >> 4) ^ (l15 & 3)) * 8);  // swizzled k-chunk

  f32x4 acc[4][4] = {};

#define STG(kt)                                                              \
  {                                                                          \
    ushort* la = (ushort*)As[(kt) % 3] + dst0;                               \
    ushort* lb = (ushort*)Bs[(kt) % 3] + dst0;                               \
    gload_lds16(ga + (kt) * 32, la);                                         \
    gload_lds16(ga + 65536 + (kt) * 32, la + 2048);                          \
    gload_lds16(gb + (kt) * 32, lb);                                         \
    gload_lds16(gb + 65536 + (kt) * 32, lb + 2048);                          \
  }

  STG(0);
  STG(1);
  for (int kt = 0; kt < 32; ++kt) {
    if (kt < 31) asm volatile("s_waitcnt vmcnt(4)" ::: "memory");
    else         asm volatile("s_waitcnt vmcnt(0)" ::: "memory");
    __builtin_amdgcn_s_barrier();
    __builtin_amdgcn_sched_barrier(0);          // no LDS-read hoist past barrier
    if (kt + 2 < 32) STG(kt + 2);
    const ushort* Ab = As[kt % 3];
    const ushort* Bb = Bs[kt % 3];
    half8 af[4], bf[4];
#pragma unroll
    for (int i = 0; i < 4; ++i) {
      af[i] = *(const half8*)&Ab[rA[i] + ck];
      bf[i] = *(const half8*)&Bb[rB[i] + ck];
    }
    __builtin_amdgcn_s_setprio(1);
#pragma unroll
    for (int i = 0; i < 4; ++i)
#pragma unroll
      for (int j = 0; j < 4; ++j)
        acc[i][j] = __builtin_amdgcn_mfma_f32_16x16x32_f16(af[i], bf[j], acc[i][j], 0, 0, 0);
    __builtin_amdgcn_s_setprio(0);
  }
#undef STG

  const int row0 = bm * 128 + wm + ((lane >> 4) << 2);
  const int colb = bn * 128 + wn + l15;
  if (EPI == 0) {
    int mat = bn >> 3;
    ushort* dst = mat == 0 ? (ushort*)o0 : mat == 1 ? (ushort*)o1 : (ushort*)o2;
    int cn0 = colb & 1023;
#pragma unroll
    for (int i = 0; i < 4; ++i)
#pragma unroll
      for (int j = 0; j < 4; ++j)
#pragma unroll
        for (int r = 0; r < 4; ++r)
          dst[(size_t)(row0 + i * 16 + r) * 1024 + cn0 + j * 16] = f2h(acc[i][j][r]);
  } else {
    float* sc = (float*)o0 + (size_t)bz * 4194304;
    float fm[4] = {-1e30f, -1e30f, -1e30f, -1e30f};
    float fz[4] = {0.f, 0.f, 0.f, 0.f};
#pragma unroll
    for (int i = 0; i < 4; ++i)
#pragma unroll
      for (int j = 0; j < 4; ++j) {
        int col = colb + j * 16;
#pragma unroll
        for (int r = 0; r < 4; ++r) {
          int row = row0 + i * 16 + r;
          bool ok = col <= row;
          float w = ok ? acc[i][j][r] * 0.03125f : -1e30f;  // 1/sqrt(1024)
          sc[(size_t)row * 2048 + col] = w;
          float nm = fmaxf(fm[j], w);
          fz[j] = fz[j] * __expf(fm[j] - nm) + (ok ? __expf(w - nm) : 0.f);
          fm[j] = nm;
        }
      }
    // reduce across lane>>4 groups (same column, different rows)
#pragma unroll
    for (int j = 0; j < 4; ++j) {
#pragma unroll
      for (int mk = 16; mk <= 32; mk <<= 1) {
        float om = __shfl_xor(fm[j], mk);
        float oz = __shfl_xor(fz[j], mk);
        float nm = fmaxf(fm[j], om);
        fz[j] = fz[j] * __expf(fm[j] - nm) + oz * __expf(om - nm);
        fm[j] = nm;
      }
    }
    if (lane < 16) {
#pragma unroll
      for (int j = 0; j < 4; ++j) {
        red[wv][j][l15][0] = fm[j];
        red[wv][j][l15][1] = fz[j];
      }
    }
    __syncthreads();
    if (t < 128) {
      int wnid = t >> 6, jj = (t >> 4) & 3, ll = t & 15;
      float m0 = red[wnid][jj][ll][0], z0 = red[wnid][jj][ll][1];
      float m1 = red[wnid + 2][jj][ll][0], z1 = red[wnid + 2][jj][ll][1];
      float nm = fmaxf(m0, m1);
      float zz = z0 * __expf(m0 - nm) + z1 * __expf(m1 - nm);
      size_t po = ((size_t)bz * 16 + bm) * 2048 + bn * 128 + wnid * 64 + jj * 16 + ll;
      pm[po] = nm;
      pz[po] = zz;
    }
  }
}

// ---- stats2: combine 16 row-tile partials per column (skip unwritten) ----
__global__ void k_stats2(const float* __restrict__ pm, const float* __restrict__ pz,
                         float* __restrict__ cm, float* __restrict__ cz) {
  int b = blockIdx.z;
  int j = blockIdx.x * 256 + threadIdx.x;
  int cmin = j >> 7;  // tiles bm < j>>7 are fully masked / never written
  float m = -1e30f;
  for (int c = cmin; c < 16; ++c)
    m = fmaxf(m, pm[((size_t)b * 16 + c) * 2048 + j]);
  float zs = 0.f;
  for (int c = cmin; c < 16; ++c) {
    float zz = pz[((size_t)b * 16 + c) * 2048 + j];
    if (zz > 0.f) zs += zz * __expf(pm[((size_t)b * 16 + c) * 2048 + j] - m);
  }
  cm[(size_t)b * 2048 + j] = m;
  cz[(size_t)b * 2048 + j] = zs > 0.f ? 1.0f / zs : 0.f;
}

// -------- PV gemm: 128x256 tiles, 8 waves; A = P (fused exp from Sc, swizzled
// ds_write), B = Vt (gload, pre-swizzled source); causal K-truncation. --------
__global__ __launch_bounds__(512)
void k_pv(const float* __restrict__ Sc, const float* __restrict__ cm,
          const float* __restrict__ cz, const ushort* __restrict__ Vt,
          float* __restrict__ out) {
  int b = blockIdx.z;
  int bm = blockIdx.y, bn = blockIdx.x;  // bn in 0..3
  const float* S = Sc + (size_t)b * 4194304;
  const float* cmb = cm + (size_t)b * 2048;
  const float* czb = cz + (size_t)b * 2048;
  const ushort* Vb = Vt + (size_t)b * 2097152;
  float* ob = out + (size_t)b * 2097152;

  __shared__ __align__(16) ushort As[128 * 64];  // swizzled: chunk ^ (row&7)
  __shared__ __align__(16) ushort Bs[256 * 64];

  const int t = threadIdx.x, lane = t & 63, wv = t >> 6;
  const int wm = (wv >> 2) * 64, wn = (wv & 3) * 64, l15 = lane & 15;
  f32x4 acc[4][4] = {};

  // B staging: row c*64 + (t>>3), source chunk inverse-swizzled
  const int srcb = (((t & 7) ^ ((t >> 3) & 7)) * 8);
  const ushort* gb = Vb + (size_t)(bn * 256 + (t >> 3)) * 2048 + srcb;
  // A exp-staging: rows it*64 + (t>>3), logical col chunk t&7
  const int ar = t >> 3;
  const int ac = (t & 7) * 8;
  const int aphys = (((t & 7) ^ ((t >> 3) & 7)) * 8);

  const int nk = 2 * bm + 2;  // P cols nonzero only for j <= 128*bm+127
  for (int kt = 0; kt < nk; ++kt) {
#pragma unroll
    for (int c = 0; c < 4; ++c)
      gload_lds16(gb + (size_t)(c * 64) * 2048 + kt * 64, &Bs[t * 8 + c * 4096]);
    int j0 = kt * 64 + ac;
    f32x4 m0 = *(const f32x4*)&cmb[j0];
    f32x4 m1 = *(const f32x4*)&cmb[j0 + 4];
    f32x4 z0 = *(const f32x4*)&czb[j0];
    f32x4 z1 = *(const f32x4*)&czb[j0 + 4];
#pragma unroll
    for (int it = 0; it < 2; ++it) {
      int row = it * 64 + ar;
      const float* src = &S[(size_t)(bm * 128 + row) * 2048 + j0];
      f32x4 a = *(const f32x4*)src;
      f32x4 c4 = *(const f32x4*)(src + 4);
      ushort8 p;
#pragma unroll
      for (int q = 0; q < 4; ++q) p[q] = f2h(__expf(a[q] - m0[q]) * z0[q]);
#pragma unroll
      for (int q = 0; q < 4; ++q) p[4 + q] = f2h(__expf(c4[q] - m1[q]) * z1[q]);
      *(ushort8*)&As[row * 64 + aphys] = p;
    }
    __syncthreads();
#pragma unroll
    for (int kk = 0; kk < 2; ++kk) {
      const int cp = ((kk * 4 + (lane >> 4)) ^ (l15 & 7)) * 8;
      half8 af[4], bf[4];
#pragma unroll
      for (int i = 0; i < 4; ++i) {
        af[i] = *(const half8*)&As[(wm + i * 16 + l15) * 64 + cp];
        bf[i] = *(const half8*)&Bs[(wn + i * 16 + l15) * 64 + cp];
      }
      __builtin_amdgcn_s_setprio(1);
#pragma unroll
      for (int i = 0; i < 4; ++i)
#pragma unroll
        for (int j = 0; j < 4; ++j)
          acc[i][j] = __builtin_amdgcn_mfma_f32_16x16x32_f16(af[i], bf[j], acc[i][j], 0, 0, 0);
      __builtin_amdgcn_s_setprio(0);
    }
    __syncthreads();
  }

  const int row0 = bm * 128 + wm + ((lane >> 4) << 2);
  const int col0 = bn * 256 + wn + l15;
#pragma unroll
  for (int i = 0; i < 4; ++i)
#pragma unroll
    for (int j = 0; j < 4; ++j) {
      int col = col0 + j * 16;
#pragma unroll
      for (int r = 0; r < 4; ++r)
        ob[(size_t)(row0 + i * 16 + r) * 1024 + col] = acc[i][j][r];
    }
}

// ---------------- host ----------------
extern "C" void kernel_launch(void* const* d_in, const int* in_sizes, int n_in,
                              void* d_out, int out_size, void* d_ws, size_t ws_size,
                              hipStream_t stream) {
  const float* x  = (const float*)d_in[0];
  const float* Wq = (const float*)d_in[1];
  const float* Wk = (const float*)d_in[2];
  const float* Wv = (const float*)d_in[3];
  float* out = (float*)d_out;
  char* ws = (char*)d_ws;

  ushort* Qh = (ushort*)(ws);                 // 16,777,216
  ushort* Kh = (ushort*)(ws + 16777216);      // 16,777,216
  ushort* Vt = (ushort*)(ws + 33554432);      // 16,777,216
  float*  Sc = (float*) (ws + 50331648);      // 4 x 2048*2048*4 = 67,108,864
  // transient (dead before Sc is written):
  ushort* xh = (ushort*)(ws + 50331648);      // dead after QKV
  ushort* Wt = (ushort*)(ws + 67108864);      // dead after QKV
  ushort* Vh = (ushort*)(ws + 73400320);      // dead after tr_v
  // stats at tail:
  float*  pm = (float*) (ws + 117440512);     // 524,288
  float*  pz = (float*) (ws + 117964800);     // 524,288
  float*  cm = (float*) (ws + 118489088);     // 32,768
  float*  cz = (float*) (ws + 118521856);     // 32,768  (end ~118.6 MB)

  k_cvt_x<<<8192, 256, 0, stream>>>(x, xh);
  k_cvt_w<<<dim3(32, 32, 3), dim3(32, 8), 0, stream>>>(Wq, Wk, Wv, Wt);
  // fused QKV projection: A = xh [8192x1024], Bt = Wt [3072x1024]
  k_gemm32<0><<<1536, 256, 0, stream>>>(xh, Wt, Qh, Kh, Vh, nullptr, nullptr);
  k_tr_v<<<dim3(32, 64, 4), dim3(32, 8), 0, stream>>>(Vh, Vt);
  // scores + fused column-stats partials, batched over z
  k_gemm32<1><<<dim3(16, 16, 4), 256, 0, stream>>>(Qh, Kh, Sc, nullptr, nullptr, pm, pz);
  k_stats2<<<dim3(8, 1, 4), 256, 0, stream>>>(pm, pz, cm, cz);
  // context: A = P(fused) [2048x2048], B = Vt (K truncated per row-block)
  k_pv<<<dim3(4, 16, 4), 512, 0, stream>>>(Sc, cm, cz, Vt, out);
}

// Round 5
// 215.746 us; speedup vs baseline: 1.2437x; 1.0983x over previous
//
#include <hip/hip_runtime.h>
#include <stdint.h>

// B=4, S=2048, d=1024. fp32 in/out, f16 MFMA internally.
// cvt(x,W) -> QKV gemm (128^2, BK=32, triple-buffer, counted vmcnt(4)) ->
// transpose V -> scores gemm (same engine, causal skip, fused column-stats) ->
// stats2 -> PV gemm (64x256 tiles, paired-bm balance, dbuf + T14 split staging).

typedef __attribute__((ext_vector_type(8))) _Float16 half8;
typedef __attribute__((ext_vector_type(4))) float f32x4;
typedef __attribute__((ext_vector_type(8))) unsigned short ushort8;

__device__ __forceinline__ ushort f2h(float f) {
  _Float16 h = (_Float16)f;
  union { _Float16 h; ushort u; } v; v.h = h; return v.u;
}

__device__ __forceinline__ void gload_lds16(const ushort* g, ushort* l) {
  __builtin_amdgcn_global_load_lds(
      (const __attribute__((address_space(1))) void*)g,
      (__attribute__((address_space(3))) void*)l, 16, 0, 0);
}

// ---------------- convert / transpose kernels ----------------
__global__ void k_cvt_x(const float* __restrict__ x, ushort* __restrict__ xh) {
  int i = (blockIdx.x * 256 + threadIdx.x) * 4;
  float4 v = *(const float4*)(x + i);
  ushort4 o;
  o.x = f2h(v.x); o.y = f2h(v.y); o.z = f2h(v.z); o.w = f2h(v.w);
  *(ushort4*)(xh + i) = o;
}

__global__ void k_cvt_w(const float* __restrict__ Wq, const float* __restrict__ Wk,
                        const float* __restrict__ Wv, ushort* __restrict__ Wt) {
  __shared__ ushort tile[32][33];
  const float* W = blockIdx.z == 0 ? Wq : blockIdx.z == 1 ? Wk : Wv;
  int e0 = blockIdx.x * 32, d0 = blockIdx.y * 32;
  for (int r = threadIdx.y; r < 32; r += 8)
    tile[r][threadIdx.x] = f2h(W[(size_t)(d0 + r) * 1024 + e0 + threadIdx.x]);
  __syncthreads();
  ushort* out = Wt + (size_t)blockIdx.z * 1024 * 1024;
  for (int r = threadIdx.y; r < 32; r += 8)
    out[(size_t)(e0 + r) * 1024 + d0 + threadIdx.x] = tile[threadIdx.x][r];
}

// V f16 [b*2048+j][e] -> Vt [b][e][j]
__global__ void k_tr_v(const ushort* __restrict__ V, ushort* __restrict__ Vt) {
  __shared__ ushort tile[32][33];
  int b = blockIdx.z;
  int e0 = blockIdx.x * 32, j0 = blockIdx.y * 32;
  const ushort* src = V + (size_t)b * 2048 * 1024;
  for (int r = threadIdx.y; r < 32; r += 8)
    tile[r][threadIdx.x] = src[(size_t)(j0 + r) * 1024 + e0 + threadIdx.x];
  __syncthreads();
  ushort* dst = Vt + (size_t)b * 1024 * 2048;
  for (int r = threadIdx.y; r < 32; r += 8)
    dst[(size_t)(e0 + r) * 2048 + j0 + threadIdx.x] = tile[threadIdx.x][r];
}

// ======= 128x128 GEMM engine: BK=32, triple-buffer, counted vmcnt(4) =======
template <int EPI>
__global__ __launch_bounds__(256)
void k_gemm32(const ushort* __restrict__ A, const ushort* __restrict__ Bt,
              void* o0, void* o1, void* o2,
              float* __restrict__ pm, float* __restrict__ pz) {
  int bm, bn, bz = 0;
  if (EPI == 0) {
    int wg = blockIdx.x;                        // 1536 = 8 * 192, bijective
    int swz = (wg & 7) * 192 + (wg >> 3);
    bm = swz / 24; bn = swz % 24;
  } else {
    bm = blockIdx.y; bn = blockIdx.x; bz = blockIdx.z;
    if (bn > bm) return;                        // fully-masked causal tile
    A  += (size_t)bz * 2097152;
    Bt += (size_t)bz * 2097152;
  }
  __shared__ __align__(16) ushort As[3][128 * 32];
  __shared__ __align__(16) ushort Bs[3][128 * 32];
  __shared__ float red[4][4][16][2];

  const int t = threadIdx.x, lane = t & 63, wv = t >> 6;
  const int wm = (wv >> 1) * 64, wn = (wv & 1) * 64, l15 = lane & 15;
  const int srcc = (((t & 3) ^ ((t >> 2) & 3)) * 8);
  const ushort* ga = A + (size_t)(bm * 128 + (t >> 2)) * 1024 + srcc;
  const ushort* gb = Bt + (size_t)(bn * 128 + (t >> 2)) * 1024 + srcc;
  const int dst0 = t * 8;

  int rA[4], rB[4];
#pragma unroll
  for (int i = 0; i < 4; ++i) {
    rA[i] = (wm + i * 16 + l15) * 32;
    rB[i] = (wn + i * 16 + l15) * 32;
  }
  const int ck = (((lane >> 4) ^ (l15 & 3)) * 8);

  f32x4 acc[4][4] = {};

#define STG(kt)                                                              \
  {                                                                          \
    ushort* la = (ushort*)As[(kt) % 3] + dst0;                               \
    ushort* lb = (ushort*)Bs[(kt) % 3] + dst0;                               \
    gload_lds16(ga + (kt) * 32, la);                                         \
    gload_lds16(ga + 65536 + (kt) * 32, la + 2048);                          \
    gload_lds16(gb + (kt) * 32, lb);                                         \
    gload_lds16(gb + 65536 + (kt) * 32, lb + 2048);                          \
  }

  STG(0);
  STG(1);
  for (int kt = 0; kt < 32; ++kt) {
    if (kt < 31) asm volatile("s_waitcnt vmcnt(4)" ::: "memory");
    else         asm volatile("s_waitcnt vmcnt(0)" ::: "memory");
    __builtin_amdgcn_s_barrier();
    __builtin_amdgcn_sched_barrier(0);
    if (kt + 2 < 32) STG(kt + 2);
    const ushort* Ab = As[kt % 3];
    const ushort* Bb = Bs[kt % 3];
    half8 af[4], bf[4];
#pragma unroll
    for (int i = 0; i < 4; ++i) {
      af[i] = *(const half8*)&Ab[rA[i] + ck];
      bf[i] = *(const half8*)&Bb[rB[i] + ck];
    }
    __builtin_amdgcn_s_setprio(1);
#pragma unroll
    for (int i = 0; i < 4; ++i)
#pragma unroll
      for (int j = 0; j < 4; ++j)
        acc[i][j] = __builtin_amdgcn_mfma_f32_16x16x32_f16(af[i], bf[j], acc[i][j], 0, 0, 0);
    __builtin_amdgcn_s_setprio(0);
  }
#undef STG

  const int row0 = bm * 128 + wm + ((lane >> 4) << 2);
  const int colb = bn * 128 + wn + l15;
  if (EPI == 0) {
    int mat = bn >> 3;
    ushort* dst = mat == 0 ? (ushort*)o0 : mat == 1 ? (ushort*)o1 : (ushort*)o2;
    int cn0 = colb & 1023;
#pragma unroll
    for (int i = 0; i < 4; ++i)
#pragma unroll
      for (int j = 0; j < 4; ++j)
#pragma unroll
        for (int r = 0; r < 4; ++r)
          dst[(size_t)(row0 + i * 16 + r) * 1024 + cn0 + j * 16] = f2h(acc[i][j][r]);
  } else {
    float* sc = (float*)o0 + (size_t)bz * 4194304;
    float fm[4] = {-1e30f, -1e30f, -1e30f, -1e30f};
    float fz[4] = {0.f, 0.f, 0.f, 0.f};
#pragma unroll
    for (int i = 0; i < 4; ++i)
#pragma unroll
      for (int j = 0; j < 4; ++j) {
        int col = colb + j * 16;
#pragma unroll
        for (int r = 0; r < 4; ++r) {
          int row = row0 + i * 16 + r;
          bool ok = col <= row;
          float w = ok ? acc[i][j][r] * 0.03125f : -1e30f;  // 1/sqrt(1024)
          sc[(size_t)row * 2048 + col] = w;
          float nm = fmaxf(fm[j], w);
          fz[j] = fz[j] * __expf(fm[j] - nm) + (ok ? __expf(w - nm) : 0.f);
          fm[j] = nm;
        }
      }
#pragma unroll
    for (int j = 0; j < 4; ++j) {
#pragma unroll
      for (int mk = 16; mk <= 32; mk <<= 1) {
        float om = __shfl_xor(fm[j], mk);
        float oz = __shfl_xor(fz[j], mk);
        float nm = fmaxf(fm[j], om);
        fz[j] = fz[j] * __expf(fm[j] - nm) + oz * __expf(om - nm);
        fm[j] = nm;
      }
    }
    if (lane < 16) {
#pragma unroll
      for (int j = 0; j < 4; ++j) {
        red[wv][j][l15][0] = fm[j];
        red[wv][j][l15][1] = fz[j];
      }
    }
    __syncthreads();
    if (t < 128) {
      int wnid = t >> 6, jj = (t >> 4) & 3, ll = t & 15;
      float m0 = red[wnid][jj][ll][0], z0 = red[wnid][jj][ll][1];
      float m1 = red[wnid + 2][jj][ll][0], z1 = red[wnid + 2][jj][ll][1];
      float nm = fmaxf(m0, m1);
      float zz = z0 * __expf(m0 - nm) + z1 * __expf(m1 - nm);
      size_t po = ((size_t)bz * 16 + bm) * 2048 + bn * 128 + wnid * 64 + jj * 16 + ll;
      pm[po] = nm;
      pz[po] = zz;
    }
  }
}

// ---- stats2: combine 16 row-tile partials per column (skip unwritten) ----
__global__ void k_stats2(const float* __restrict__ pm, const float* __restrict__ pz,
                         float* __restrict__ cm, float* __restrict__ cz) {
  int b = blockIdx.z;
  int j = blockIdx.x * 256 + threadIdx.x;
  int cmin = j >> 7;
  float m = -1e30f;
  for (int c = cmin; c < 16; ++c)
    m = fmaxf(m, pm[((size_t)b * 16 + c) * 2048 + j]);
  float zs = 0.f;
  for (int c = cmin; c < 16; ++c) {
    float zz = pz[((size_t)b * 16 + c) * 2048 + j];
    if (zz > 0.f) zs += zz * __expf(pm[((size_t)b * 16 + c) * 2048 + j] - m);
  }
  cm[(size_t)b * 2048 + j] = m;
  cz[(size_t)b * 2048 + j] = zs > 0.f ? 1.0f / zs : 0.f;
}

// ===== PV gemm: 64x256 tiles, 512 blocks (paired bm), dbuf + T14 staging =====
// A = P (fused exp from Sc, reg-staged, swizzled ds_write), B = Vt (gload,
// pre-swizzled source), counted vmcnt(16) mid-loop; nk = bm+1 (BK=64).
__global__ __launch_bounds__(256, 2)
void k_pv(const float* __restrict__ Sc, const float* __restrict__ cm,
          const float* __restrict__ cz, const ushort* __restrict__ Vt,
          float* __restrict__ out) {
  const int wg = blockIdx.x;
  const int half = wg >> 8, q = wg & 255;
  const int bn = q & 3, bmi = (q >> 2) & 31;
  const int z = (q >> 7) + 2 * half;
  const int bm = half ? 31 - bmi : bmi;   // CU pairing: bm + bm' = 31
  const float* S = Sc + (size_t)z * 4194304;
  const float* cmb = cm + (size_t)z * 2048;
  const float* czb = cz + (size_t)z * 2048;
  const ushort* Vb = Vt + (size_t)z * 2097152;
  float* ob = out + (size_t)z * 2097152;

  __shared__ __align__(16) ushort As[2][64 * 64];    // 16 KB
  __shared__ __align__(16) ushort Bs[2][256 * 64];   // 64 KB

  const int t = threadIdx.x, lane = t & 63, wv = t >> 6;
  const int wn = wv * 64, l15 = lane & 15;
  const int nk = bm + 1;

  const int tr = t >> 3;                       // 0..31
  const int lc = (t & 7) ^ (tr & 7);           // logical 16B chunk (swizzle inv)
  const ushort* gB = Vb + (size_t)(bn * 256 + tr) * 2048 + lc * 8;
  const float*  gS = S + (size_t)(bm * 64 + tr) * 2048 + lc * 8;

  f32x4 acc[4][4] = {};
  // two named A-staging register sets (rule 20: static indexing only)
  f32x4 a0_0, a1_0, a2_0, a3_0, m0_0, m1_0, z0_0, z1_0;
  f32x4 a0_1, a1_1, a2_1, a3_1, m0_1, m1_1, z0_1, z1_1;

#define IB(kt, buf)                                                           \
  {                                                                           \
    ushort* lb = (ushort*)Bs[buf] + t * 8;                                    \
    const ushort* src = gB + (kt) * 64;                                       \
    _Pragma("unroll") for (int g2 = 0; g2 < 8; ++g2)                          \
        gload_lds16(src + (size_t)(g2 * 32) * 2048, lb + g2 * 2048);          \
  }
#define IA(kt, A0, A1, A2, A3, M0, M1, Z0, Z1)                                \
  {                                                                           \
    const float* sp = gS + (kt) * 64;                                         \
    A0 = *(const f32x4*)sp;                                                   \
    A1 = *(const f32x4*)(sp + 4);                                             \
    A2 = *(const f32x4*)(sp + 32 * 2048);                                     \
    A3 = *(const f32x4*)(sp + 32 * 2048 + 4);                                 \
    const float* mp = cmb + (kt) * 64 + lc * 8;                               \
    const float* zp = czb + (kt) * 64 + lc * 8;                               \
    M0 = *(const f32x4*)mp; M1 = *(const f32x4*)(mp + 4);                     \
    Z0 = *(const f32x4*)zp; Z1 = *(const f32x4*)(zp + 4);                     \
  }
#define EW(buf, A0, A1, A2, A3, M0, M1, Z0, Z1)                               \
  {                                                                           \
    ushort8 p;                                                                \
    _Pragma("unroll") for (int qq = 0; qq < 4; ++qq) {                        \
      p[qq] = f2h(__expf(A0[qq] - M0[qq]) * Z0[qq]);                          \
      p[4 + qq] = f2h(__expf(A1[qq] - M1[qq]) * Z1[qq]);                      \
    }                                                                         \
    *(ushort8*)&As[buf][t * 8] = p;                                           \
    _Pragma("unroll") for (int qq = 0; qq < 4; ++qq) {                        \
      p[qq] = f2h(__expf(A2[qq] - M0[qq]) * Z0[qq]);                          \
      p[4 + qq] = f2h(__expf(A3[qq] - M1[qq]) * Z1[qq]);                      \
    }                                                                         \
    *(ushort8*)&As[buf][t * 8 + 2048] = p;                                    \
  }
#define COMP(buf)                                                             \
  {                                                                           \
    _Pragma("unroll") for (int kk = 0; kk < 2; ++kk) {                        \
      const int cpk = (((kk * 4) + (lane >> 4)) ^ (l15 & 7)) * 8;             \
      half8 af[4], bf[4];                                                     \
      _Pragma("unroll") for (int i = 0; i < 4; ++i) {                         \
        af[i] = *(const half8*)&As[buf][(i * 16 + l15) * 64 + cpk];           \
        bf[i] = *(const half8*)&Bs[buf][(wn + i * 16 + l15) * 64 + cpk];      \
      }                                                                       \
      __builtin_amdgcn_s_setprio(1);                                          \
      _Pragma("unroll") for (int i = 0; i < 4; ++i)                           \
          _Pragma("unroll") for (int j = 0; j < 4; ++j)                       \
          acc[i][j] = __builtin_amdgcn_mfma_f32_16x16x32_f16(                 \
              af[i], bf[i == i ? j : j], acc[i][j], 0, 0, 0);                 \
      __builtin_amdgcn_s_setprio(0);                                         \
    }                                                                         \
  }
#define BODY(buf, nbuf, S2, S3)                                               \
  {                                                                           \
    if (kt + 1 < nk) asm volatile("s_waitcnt vmcnt(16)" ::: "memory");        \
    else             asm volatile("s_waitcnt vmcnt(0)" ::: "memory");         \
    __builtin_amdgcn_s_barrier();                                             \
    __builtin_amdgcn_sched_barrier(0);                                        \
    COMP(buf);                                                                \
    if (kt + 1 < nk) {                                                        \
      EW(nbuf, a0_##S2, a1_##S2, a2_##S2, a3_##S2, m0_##S2, m1_##S2,          \
         z0_##S2, z1_##S2);                                                   \
    }                                                                         \
    asm volatile("s_waitcnt lgkmcnt(0)" ::: "memory");                        \
    __builtin_amdgcn_s_barrier();                                             \
    __builtin_amdgcn_sched_barrier(0);                                        \
    if (kt + 2 < nk) {                                                        \
      IA(kt + 2, a0_##S3, a1_##S3, a2_##S3, a3_##S3, m0_##S3, m1_##S3,        \
         z0_##S3, z1_##S3);                                                   \
      IB(kt + 2, buf);                                                        \
    }                                                                         \
  }

  // prologue
  IA(0, a0_0, a1_0, a2_0, a3_0, m0_0, m1_0, z0_0, z1_0);
  IB(0, 0);
  EW(0, a0_0, a1_0, a2_0, a3_0, m0_0, m1_0, z0_0, z1_0);
  if (nk > 1) {
    IA(1, a0_1, a1_1, a2_1, a3_1, m0_1, m1_1, z0_1, z1_1);
    IB(1, 1);
  }
  int kt = 0;
  while (true) {
    BODY(0, 1, 1, 0);      // compute buf0; expwrite set1->As[1]; issue kt+2->set0,Bs[0]
    ++kt; if (kt >= nk) break;
    BODY(1, 0, 0, 1);
    ++kt; if (kt >= nk) break;
  }
#undef IB
#undef IA
#undef EW
#undef COMP
#undef BODY

  const int row0 = bm * 64 + ((lane >> 4) << 2);
  const int col0 = bn * 256 + wn + l15;
#pragma unroll
  for (int i = 0; i < 4; ++i)
#pragma unroll
    for (int j = 0; j < 4; ++j) {
      int col = col0 + j * 16;
#pragma unroll
      for (int r = 0; r < 4; ++r)
        ob[(size_t)(row0 + i * 16 + r) * 1024 + col] = acc[i][j][r];
    }
}

// ---------------- host ----------------
extern "C" void kernel_launch(void* const* d_in, const int* in_sizes, int n_in,
                              void* d_out, int out_size, void* d_ws, size_t ws_size,
                              hipStream_t stream) {
  const float* x  = (const float*)d_in[0];
  const float* Wq = (const float*)d_in[1];
  const float* Wk = (const float*)d_in[2];
  const float* Wv = (const float*)d_in[3];
  float* out = (float*)d_out;
  char* ws = (char*)d_ws;

  ushort* Qh = (ushort*)(ws);                 // 16,777,216
  ushort* Kh = (ushort*)(ws + 16777216);      // 16,777,216
  ushort* Vt = (ushort*)(ws + 33554432);      // 16,777,216
  float*  Sc = (float*) (ws + 50331648);      // 4 x 2048*2048*4 = 67,108,864
  // transient (dead before Sc is written):
  ushort* xh = (ushort*)(ws + 50331648);      // dead after QKV
  ushort* Wt = (ushort*)(ws + 67108864);      // dead after QKV
  ushort* Vh = (ushort*)(ws + 73400320);      // dead after tr_v
  // stats at tail:
  float*  pm = (float*) (ws + 117440512);     // 524,288
  float*  pz = (float*) (ws + 117964800);     // 524,288
  float*  cm = (float*) (ws + 118489088);     // 32,768
  float*  cz = (float*) (ws + 118521856);     // 32,768  (end ~118.6 MB)

  k_cvt_x<<<8192, 256, 0, stream>>>(x, xh);
  k_cvt_w<<<dim3(32, 32, 3), dim3(32, 8), 0, stream>>>(Wq, Wk, Wv, Wt);
  k_gemm32<0><<<1536, 256, 0, stream>>>(xh, Wt, Qh, Kh, Vh, nullptr, nullptr);
  k_tr_v<<<dim3(32, 64, 4), dim3(32, 8), 0, stream>>>(Vh, Vt);
  k_gemm32<1><<<dim3(16, 16, 4), 256, 0, stream>>>(Qh, Kh, Sc, nullptr, nullptr, pm, pz);
  k_stats2<<<dim3(8, 1, 4), 256, 0, stream>>>(pm, pz, cm, cz);
  k_pv<<<512, 256, 0, stream>>>(Sc, cm, cz, Vt, out);
}